// Round 17
// baseline (182.164 us; speedup 1.0000x reference)
//
#include <hip/hip_runtime.h>
#include <cstdint>

typedef __bf16 bf16x8 __attribute__((ext_vector_type(8)));
typedef __bf16 bf16x4 __attribute__((ext_vector_type(4)));
typedef short  s16x8  __attribute__((ext_vector_type(8)));
typedef float  f32x4  __attribute__((ext_vector_type(4)));
typedef unsigned int uint32;
typedef uint32 u32x2 __attribute__((ext_vector_type(2)));
typedef unsigned long long u64;

#define SB 2048
#define DD 1024
#define HH 16
#define HDD 64
#define BB 2
#define C2LOG 0.2434547882f        /* (1.35/sqrt(64)) * log2(e)  — folded into Q */
#define NEGBIG2 (-1.9476383e9f)    /* -1e9 * 1.35 * log2(e) */

__device__ __forceinline__ ushort f2bf(float f){
  uint32 u = __builtin_bit_cast(uint32, f);
  u += 0x7fffu + ((u >> 16) & 1u);
  return (ushort)(u >> 16);
}
__device__ __forceinline__ bf16x8 ldb128(const void* p){
  return __builtin_bit_cast(bf16x8, *(const s16x8*)p);
}
__device__ __forceinline__ void gl_lds16(const void* g, void* l){
  __builtin_amdgcn_global_load_lds((const __attribute__((address_space(1))) void*)g,
                                   (__attribute__((address_space(3))) void*)l, 16, 0, 0);
}
// raw v_exp_f32 (D = 2^S0)
__device__ __forceinline__ float exp2r(float x){
  float r; asm("v_exp_f32 %0, %1" : "=v"(r) : "v"(x)); return r;
}

// ---------------- fused prep: pack mask + cvt x + cvt 4 weights --------------
__global__ __launch_bounds__(256) void k_prep(
    const float* __restrict__ x, const int* __restrict__ mask,
    const float* __restrict__ Wq, const float* __restrict__ Wk,
    const float* __restrict__ Wv, const float* __restrict__ Wo,
    ushort* __restrict__ xb, u64* __restrict__ bits,
    ushort* __restrict__ wqb, ushort* __restrict__ wkb,
    ushort* __restrict__ wvb, ushort* __restrict__ wob)
{
  int bid = blockIdx.x;
  if (bid < 32768){
    int i = bid * 256 + threadIdx.x;
    u64 bm = __ballot(mask[i] != 0);
    if ((threadIdx.x & 63) == 0) bits[i >> 6] = bm;
  } else if (bid < 36864){
    int i = (bid - 32768) * 256 + threadIdx.x;
    float4 v = ((const float4*)x)[i];
    ushort4 o;
    o.x = f2bf(v.x); o.y = f2bf(v.y); o.z = f2bf(v.z); o.w = f2bf(v.w);
    ((ushort4*)xb)[i] = o;
  } else {
    int sub = bid - 36864;
    int zz = sub >> 10;
    const float* in = (zz == 0) ? Wq : (zz == 1) ? Wk : (zz == 2) ? Wv : Wo;
    ushort* out     = (zz == 0) ? wqb : (zz == 1) ? wkb : (zz == 2) ? wvb : wob;
    int i = (sub & 1023) * 256 + threadIdx.x;
    float4 v = ((const float4*)in)[i];
    ushort4 o;
    o.x = f2bf(v.x); o.y = f2bf(v.y); o.z = f2bf(v.z); o.w = f2bf(v.w);
    ((ushort4*)out)[i] = o;
  }
}

// ---------------- generic GEMM (double-buffered): C = (A W^T + bias)*scl -----
template<int MODE>
__device__ __forceinline__ void gemm_body(
    const ushort* __restrict__ A, const ushort* __restrict__ W,
    const float* __restrict__ bias, float scl,
    ushort* __restrict__ outp, float* __restrict__ outf,
    int rowBase, int colBase, ushort* lsA, ushort* lsB)
{
  const int t = threadIdx.x;
  const int l = t & 63, w = t >> 6;
  const int g16 = l >> 4, r16 = l & 15;
  const int wr = w >> 1, wc = w & 1;
  f32x4 zero = {0.f, 0.f, 0.f, 0.f};
  f32x4 acc[4][4];
  #pragma unroll
  for (int m = 0; m < 4; m++)
    #pragma unroll
    for (int n = 0; n < 4; n++) acc[m][n] = zero;

  auto stage = [&](int kt, int buf){
    #pragma unroll
    for (int i = 0; i < 2; i++){
      int c = t + i * 256;
      int row = c >> 2, cin = c & 3;
      int g = cin ^ ((row >> 1) & 3);
      gl_lds16(A + (size_t)(rowBase + row) * DD + kt * 32 + g * 8, (char*)lsA + buf * 8192 + c * 16);
      gl_lds16(W + (size_t)(colBase + row) * DD + kt * 32 + g * 8, (char*)lsB + buf * 8192 + c * 16);
    }
  };
  stage(0, 0);
  int cur = 0;
  for (int kt = 0; kt < 32; ++kt){
    __syncthreads();
    if (kt + 1 < 32) stage(kt + 1, cur ^ 1);
    bf16x8 af[4], bfr[4];
    #pragma unroll
    for (int m = 0; m < 4; m++){
      int row = wr * 64 + m * 16 + r16;
      af[m] = ldb128((char*)lsA + cur * 8192 + row * 64 + ((g16 ^ ((row >> 1) & 3)) << 4));
    }
    #pragma unroll
    for (int n = 0; n < 4; n++){
      int row = wc * 64 + n * 16 + r16;
      bfr[n] = ldb128((char*)lsB + cur * 8192 + row * 64 + ((g16 ^ ((row >> 1) & 3)) << 4));
    }
    #pragma unroll
    for (int m = 0; m < 4; m++)
      #pragma unroll
      for (int n = 0; n < 4; n++)
        acc[m][n] = __builtin_amdgcn_mfma_f32_16x16x32_bf16(af[m], bfr[n], acc[m][n], 0, 0, 0);
    cur ^= 1;
  }
  #pragma unroll
  for (int m = 0; m < 4; m++){
    #pragma unroll
    for (int n = 0; n < 4; n++){
      int ng = colBase + wc * 64 + n * 16 + r16;
      float bval = bias[ng];
      if (MODE == 2){
        int h = ng >> 6, d = ng & 63;
        int s0 = rowBase + wr * 64 + m * 16 + g16 * 4;
        int b = s0 >> 11, s = s0 & 2047;
        ushort4 o;
        o.x = f2bf((acc[m][n][0] + bval) * scl);
        o.y = f2bf((acc[m][n][1] + bval) * scl);
        o.z = f2bf((acc[m][n][2] + bval) * scl);
        o.w = f2bf((acc[m][n][3] + bval) * scl);
        *(ushort4*)(outp + ((size_t)(b * HH + h) * HDD + d) * SB + s) = o;
      } else {
        #pragma unroll
        for (int j = 0; j < 4; j++){
          int r = rowBase + wr * 64 + m * 16 + g16 * 4 + j;
          float v = (acc[m][n][j] + bval) * scl;
          if (MODE == 0){
            int h = ng >> 6, d = ng & 63;
            int b = r >> 11, s = r & 2047;
            outp[(((size_t)(b * HH + h) * SB + s) << 6) + d] = f2bf(v);
          } else {
            outf[(size_t)r * DD + ng] = v;
          }
        }
      }
    }
  }
}

// XCD-aware 8x4 patch decode (bijective) for 32x8 tile grids
__device__ __forceinline__ void xcd_patch2(int bid, int& rowBase, int& colBase){
  int xcd = bid & 7, i = bid >> 3;
  rowBase = ((xcd & 3) * 8 + (i & 7)) * 128;
  colBase = ((xcd >> 2) * 4 + (i >> 3)) * 128;
}

// fused QKV projection: z=0 -> Q (scaled), z=1 -> K, z=2 -> Vt (transposed)
__global__ __launch_bounds__(256) void k_gemm_qkv(
    const ushort* __restrict__ A,
    const ushort* __restrict__ Wq, const ushort* __restrict__ Wk, const ushort* __restrict__ Wv,
    const float* __restrict__ bq, const float* __restrict__ bk, const float* __restrict__ bv,
    ushort* __restrict__ Q, ushort* __restrict__ K, ushort* __restrict__ Vt)
{
  __shared__ ushort lsA[2][4096];
  __shared__ ushort lsB[2][4096];
  int rowBase, colBase;
  xcd_patch2(blockIdx.x + blockIdx.y * 8, rowBase, colBase);
  int z = blockIdx.z;
  if (z == 0)      gemm_body<0>(A, Wq, bq, C2LOG, Q, nullptr, rowBase, colBase, &lsA[0][0], &lsB[0][0]);
  else if (z == 1) gemm_body<0>(A, Wk, bk, 1.0f, K, nullptr, rowBase, colBase, &lsA[0][0], &lsB[0][0]);
  else             gemm_body<2>(A, Wv, bv, 1.0f, Vt, nullptr, rowBase, colBase, &lsA[0][0], &lsB[0][0]);
}

// ---------------- flash attention: 8 waves x 32 q, KVBLK=128 super-tiles -----
// (EXACT r16-passing body)
__device__ __forceinline__ void stage_kv2(const ushort* __restrict__ Kp,
                                          const ushort* __restrict__ Vp,
                                          ushort* dK, ushort* dV, int t){
  #pragma unroll
  for (int i = 0; i < 2; ++i){
    int c = t + 512 * i;
    int r = c >> 3, g = (c & 7) ^ (r & 7);
    gl_lds16(Kp + (size_t)r * HDD + g * 8, (char*)dK + c * 16);
  }
  #pragma unroll
  for (int i = 0; i < 2; ++i){
    int c = t + 512 * i;
    int r = c >> 4, cc = c & 15;
    int g = ((cc & 7) ^ (r & 7)) | (cc & 8);
    gl_lds16(Vp + (size_t)r * SB + g * 8, (char*)dV + c * 16);
  }
}

__global__ __launch_bounds__(512) void k_flash(
    const ushort* __restrict__ Q, const ushort* __restrict__ K, const ushort* __restrict__ Vt,
    const u64* __restrict__ mbits,
    ushort* __restrict__ att, float* __restrict__ ilarr)
{
  __shared__ ushort lsK[2][8192];
  __shared__ ushort lsV[2][10240];   // 80 rows x 128 cols
  __shared__ ushort lsP[8][2048];
  const int t = threadIdx.x;
  const int l = t & 63, w = t >> 6;
  const int g16 = l >> 4, r16 = l & 15;
  const int bid = blockIdx.x;
  const int qt = (bid >> 3) & 7;
  const int hb = (bid >> 6) * 8 + (bid & 7);
  const int h = hb & 15, b = hb >> 4;
  const size_t ho = ((size_t)(b * HH + h)) * SB * HDD;
  const int qa = qt * 256 + w * 32 + r16;   // q-group a
  const int qb = qa + 16;                   // q-group b

  bf16x8 aqa[2], aqb[2];
  #pragma unroll
  for (int ks = 0; ks < 2; ++ks){
    aqa[ks] = ldb128(Q + ho + (size_t)qa * HDD + ks * 32 + g16 * 8);
    aqb[ks] = ldb128(Q + ho + (size_t)qb * HDD + ks * 32 + g16 * 8);
  }
  const u64* mpa = mbits + ((size_t)b * SB + qa) * 32;
  const u64* mpb = mbits + ((size_t)b * SB + qb) * 32;

  f32x4 zero = {0.f, 0.f, 0.f, 0.f};
  f32x4 accA[4], accB[4], accLA = zero, accLB = zero;
  #pragma unroll
  for (int c = 0; c < 4; c++){ accA[c] = zero; accB[c] = zero; }

  if (t < 256) lsV[t >> 7][8192 + (t & 127)] = 0x3F80;

  const ushort* Kb = K + ho;
  const ushort* Vb = Vt + ho;
  stage_kv2(Kb, Vb, &lsK[0][0], &lsV[0][0], t);

  int cur = 0;
  for (int kk = 0; kk < 16; ++kk){
    __syncthreads();
    if (kk + 1 < 16)
      stage_kv2(Kb + (size_t)(kk + 1) * 128 * HDD, Vb + (size_t)(kk + 1) * 128,
                &lsK[cur ^ 1][0], &lsV[cur ^ 1][0], t);

    #pragma unroll
    for (int h2 = 0; h2 < 2; ++h2){
      const char* lk = (const char*)&lsK[cur][0] + h2 * 8192;
      const char* lv = (const char*)&lsV[cur][0] + h2 * 128;
      char* lp = (char*)&lsP[w][0];

      f32x4 za[4], zb[4];
      __builtin_amdgcn_s_setprio(1);
      #pragma unroll
      for (int f = 0; f < 4; ++f){
        za[f] = zero; zb[f] = zero;
        int row = 16 * f + r16;
        #pragma unroll
        for (int ks = 0; ks < 2; ++ks){
          bf16x8 kf = ldb128(lk + row * 128 + ((((ks << 2) + g16) ^ (row & 7)) << 4));
          za[f] = __builtin_amdgcn_mfma_f32_16x16x32_bf16(kf, aqa[ks], za[f], 0, 0, 0);
          zb[f] = __builtin_amdgcn_mfma_f32_16x16x32_bf16(kf, aqb[ks], zb[f], 0, 0, 0);
        }
      }
      __builtin_amdgcn_s_setprio(0);

      u64 mwa = mpa[2 * kk + h2], mwb = mpb[2 * kk + h2];
      float pa[4][4], pb[4][4];
      if (__all((mwa & mwb) == ~0ull)){
        #pragma unroll
        for (int f = 0; f < 4; ++f)
          #pragma unroll
          for (int j = 0; j < 4; ++j){
            pa[f][j] = exp2r(za[f][j]);
            pb[f][j] = exp2r(zb[f][j]);
          }
      } else {
        #pragma unroll
        for (int f = 0; f < 4; ++f)
          #pragma unroll
          for (int j = 0; j < 4; ++j){
            int bit = 16 * f + 4 * g16 + j;
            pa[f][j] = exp2r(((mwa >> bit) & 1ull) ? za[f][j] : NEGBIG2);
            pb[f][j] = exp2r(((mwb >> bit) & 1ull) ? zb[f][j] : NEGBIG2);
          }
      }

      {
        int wba = r16 * 128 + ((g16 & 1) << 3);
        int wbb = (r16 + 16) * 128 + ((g16 & 1) << 3);
        #pragma unroll
        for (int f = 0; f < 4; ++f){
          bf16x4 va_ = { (__bf16)pa[f][0], (__bf16)pa[f][1], (__bf16)pa[f][2], (__bf16)pa[f][3] };
          bf16x4 vb_ = { (__bf16)pb[f][0], (__bf16)pb[f][1], (__bf16)pb[f][2], (__bf16)pb[f][3] };
          int sw = ((2 * f + (g16 >> 1)) ^ (r16 & 7)) << 4;
          *(u32x2*)(lp + wba + sw) = __builtin_bit_cast(u32x2, va_);
          *(u32x2*)(lp + wbb + sw) = __builtin_bit_cast(u32x2, vb_);
        }
      }
      bf16x8 pfA[2], pfB[2];
      #pragma unroll
      for (int ks = 0; ks < 2; ++ks){
        int sw = (((ks << 2) + g16) ^ (r16 & 7)) << 4;
        pfA[ks] = ldb128(lp + r16 * 128 + sw);
        pfB[ks] = ldb128(lp + (r16 + 16) * 128 + sw);
      }

      __builtin_amdgcn_s_setprio(1);
      #pragma unroll
      for (int c = 0; c < 4; ++c){
        int row = 16 * c + r16;
        #pragma unroll
        for (int ks = 0; ks < 2; ++ks){
          bf16x8 vf = ldb128(lv + row * 256 + ((((ks << 2) + g16) ^ (row & 7)) << 4));
          accA[c] = __builtin_amdgcn_mfma_f32_16x16x32_bf16(vf, pfA[ks], accA[c], 0, 0, 0);
          accB[c] = __builtin_amdgcn_mfma_f32_16x16x32_bf16(vf, pfB[ks], accB[c], 0, 0, 0);
        }
      }
      {
        int row = 64 + r16;
        #pragma unroll
        for (int ks = 0; ks < 2; ++ks){
          bf16x8 of = ldb128(lv + row * 256 + ((((ks << 2) + g16) ^ (row & 7)) << 4));
          accLA = __builtin_amdgcn_mfma_f32_16x16x32_bf16(of, pfA[ks], accLA, 0, 0, 0);
          accLB = __builtin_amdgcn_mfma_f32_16x16x32_bf16(of, pfB[ks], accLB, 0, 0, 0);
        }
      }
      __builtin_amdgcn_s_setprio(0);
    }
    cur ^= 1;
  }

  float ila = 1.0f / __shfl(accLA[0], r16);
  float ilb = 1.0f / __shfl(accLB[0], r16);
  #pragma unroll
  for (int c = 0; c < 4; ++c){
    ushort4 oa, ob;
    oa.x = f2bf(accA[c][0] * ila); oa.y = f2bf(accA[c][1] * ila);
    oa.z = f2bf(accA[c][2] * ila); oa.w = f2bf(accA[c][3] * ila);
    ob.x = f2bf(accB[c][0] * ilb); ob.y = f2bf(accB[c][1] * ilb);
    ob.z = f2bf(accB[c][2] * ilb); ob.w = f2bf(accB[c][3] * ilb);
    *(ushort4*)(att + ((size_t)b * SB + qa) * DD + h * HDD + c * 16 + 4 * g16) = oa;
    *(ushort4*)(att + ((size_t)b * SB + qb) * DD + h * HDD + c * 16 + 4 * g16) = ob;
  }
  if (g16 == 0){
    ilarr[(size_t)(b * HH + h) * SB + qa] = ila;
    ilarr[(size_t)(b * HH + h) * SB + qb] = ilb;
  }
}

// ---------------- fused avg + out-GEMM (grid-range split, 48 KB LDS union) ---
// blocks [0,128): 8-wave out-GEMM, 128x256 tile (all waves compute).
// blocks [128,384): avg, 256q x 128k, 2 q-groups/wave sharing K fragments.
__global__ __launch_bounds__(512) void k_avg_out(
    const ushort* __restrict__ att, const ushort* __restrict__ wob,
    const float* __restrict__ bo, float* __restrict__ out,
    const ushort* __restrict__ Q, const ushort* __restrict__ K,
    const u64* __restrict__ mbits,
    const float* __restrict__ ilarr, float* __restrict__ avg)
{
  __shared__ ushort smem[24576];   // 48 KB
  const int bid = blockIdx.x;
  const int t = threadIdx.x;
  const int l = t & 63, w = t >> 6;
  const int g16 = l >> 4, r16 = l & 15;
  f32x4 zero = {0.f, 0.f, 0.f, 0.f};

  if (bid < 128){
    // ---- 8-wave out-GEMM: 128 rows x 256 cols per block ----
    int xcd = bid & 7, i = bid >> 3;               // i in [0,16)
    int rowBase = ((xcd & 3) * 8 + (i & 7)) * 128;
    int colBase = ((xcd >> 2) * 2 + (i >> 3)) * 256;
    ushort* lsA = smem;            // 2 bufs x 8 KB
    ushort* lsB = smem + 8192;     // 2 bufs x 16 KB
    const int wr = w >> 2, wc = w & 3;
    f32x4 acc[4][4];
    #pragma unroll
    for (int m = 0; m < 4; m++)
      #pragma unroll
      for (int n = 0; n < 4; n++) acc[m][n] = zero;

    auto stage = [&](int kt, int buf){
      {
        int c = t;                                  // A: 512 chunks
        int row = c >> 2, cin = c & 3;
        int g = cin ^ ((row >> 1) & 3);
        gl_lds16(att + (size_t)(rowBase + row) * DD + kt * 32 + g * 8,
                 (char*)lsA + buf * 8192 + c * 16);
      }
      #pragma unroll
      for (int ii = 0; ii < 2; ++ii){               // B: 1024 chunks
        int c = t + ii * 512;
        int row = c >> 2, cin = c & 3;
        int g = cin ^ ((row >> 1) & 3);
        gl_lds16(wob + (size_t)(colBase + row) * DD + kt * 32 + g * 8,
                 (char*)lsB + buf * 16384 + c * 16);
      }
    };
    stage(0, 0);
    int cur = 0;
    for (int kt = 0; kt < 32; ++kt){
      __syncthreads();
      if (kt + 1 < 32) stage(kt + 1, cur ^ 1);
      bf16x8 af[4], bfr[4];
      #pragma unroll
      for (int m = 0; m < 4; m++){
        int row = wr * 64 + m * 16 + r16;
        af[m] = ldb128((char*)lsA + cur * 8192 + row * 64 + ((g16 ^ ((row >> 1) & 3)) << 4));
      }
      #pragma unroll
      for (int n = 0; n < 4; n++){
        int row = wc * 64 + n * 16 + r16;
        bfr[n] = ldb128((char*)lsB + cur * 16384 + row * 64 + ((g16 ^ ((row >> 1) & 3)) << 4));
      }
      #pragma unroll
      for (int m = 0; m < 4; m++)
        #pragma unroll
        for (int n = 0; n < 4; n++)
          acc[m][n] = __builtin_amdgcn_mfma_f32_16x16x32_bf16(af[m], bfr[n], acc[m][n], 0, 0, 0);
      cur ^= 1;
    }
    #pragma unroll
    for (int m = 0; m < 4; m++)
      #pragma unroll
      for (int n = 0; n < 4; n++){
        int ng = colBase + wc * 64 + n * 16 + r16;
        float bval = bo[ng];
        #pragma unroll
        for (int j = 0; j < 4; j++){
          int r = rowBase + wr * 64 + m * 16 + g16 * 4 + j;
          out[(size_t)r * DD + ng] = acc[m][n][j] + bval;
        }
      }
    return;
  }

  // ---- avg block: 256 q x 128 k, 2 q-groups per wave ----
  const int bid2 = bid - 128;
  const int kt = bid2 & 15, qt = (bid2 >> 4) & 7, b = bid2 >> 7;
  ushort* lsQ = smem;            // [256][64] = 32 KB
  ushort* lsK = smem + 16384;    // [128][64] = 16 KB
  const int qbase = qt * 256, kbase = kt * 128;
  const int qr0 = qbase + w * 16 + g16 * 4;   // group A rows
  const int qr1 = qr0 + 128;                  // group B rows

  u64 andv = ~0ull;
  #pragma unroll
  for (int j = 0; j < 4; ++j)
    #pragma unroll
    for (int wd = 0; wd < 2; ++wd){
      andv &= mbits[((size_t)b * SB + qr0 + j) * 32 + 2 * kt + wd];
      andv &= mbits[((size_t)b * SB + qr1 + j) * 32 + 2 * kt + wd];
    }
  bool fast = __all(andv == ~0ull);

  f32x4 accA[8], accB[8];
  #pragma unroll
  for (int f = 0; f < 8; f++){ accA[f] = zero; accB[f] = zero; }

  const size_t hstep = (size_t)SB * HDD;
  const ushort* Qp = Q + (size_t)b * HH * hstep + (size_t)qbase * HDD;
  const ushort* Kp = K + (size_t)b * HH * hstep + (size_t)kbase * HDD;

  for (int h = 0; h < HH; ++h){
    __syncthreads();          // previous head's reads complete
    #pragma unroll
    for (int i = 0; i < 4; ++i){          // Q: 2048 chunks (256 rows)
      int c = t + i * 512;
      int r = c >> 3, g = (c & 7) ^ (r & 7);
      gl_lds16(Qp + (size_t)h * hstep + (size_t)r * HDD + g * 8, (char*)lsQ + c * 16);
    }
    #pragma unroll
    for (int i = 0; i < 2; ++i){          // K: 1024 chunks (128 rows)
      int c = t + i * 512;
      int r = c >> 3, g = (c & 7) ^ (r & 7);
      gl_lds16(Kp + (size_t)h * hstep + (size_t)r * HDD + g * 8, (char*)lsK + c * 16);
    }
    __syncthreads();          // staged (barrier drains vmcnt)

    int qrow = w * 16 + r16;
    int qrow2 = qrow + 128;
    bf16x8 a0 = ldb128((char*)lsQ + qrow * 128 + (((0 + g16) ^ (qrow & 7)) << 4));
    bf16x8 a1 = ldb128((char*)lsQ + qrow * 128 + (((4 + g16) ^ (qrow & 7)) << 4));
    bf16x8 c0 = ldb128((char*)lsQ + qrow2 * 128 + (((0 + g16) ^ (qrow2 & 7)) << 4));
    bf16x8 c1 = ldb128((char*)lsQ + qrow2 * 128 + (((4 + g16) ^ (qrow2 & 7)) << 4));
    float ilhA[4], ilhB[4];
    #pragma unroll
    for (int j = 0; j < 4; j++){
      ilhA[j] = ilarr[(size_t)(b * HH + h) * SB + qr0 + j];
      ilhB[j] = ilarr[(size_t)(b * HH + h) * SB + qr1 + j];
    }

    #pragma unroll
    for (int f = 0; f < 8; ++f){
      int row = 16 * f + r16;
      bf16x8 b0 = ldb128((char*)lsK + row * 128 + (((0 + g16) ^ (row & 7)) << 4));
      bf16x8 b1 = ldb128((char*)lsK + row * 128 + (((4 + g16) ^ (row & 7)) << 4));
      f32x4 zA = zero, zB = zero;
      zA = __builtin_amdgcn_mfma_f32_16x16x32_bf16(a0, b0, zA, 0, 0, 0);
      zA = __builtin_amdgcn_mfma_f32_16x16x32_bf16(a1, b1, zA, 0, 0, 0);
      zB = __builtin_amdgcn_mfma_f32_16x16x32_bf16(c0, b0, zB, 0, 0, 0);
      zB = __builtin_amdgcn_mfma_f32_16x16x32_bf16(c1, b1, zB, 0, 0, 0);
      if (fast){
        #pragma unroll
        for (int j = 0; j < 4; j++){
          accA[f][j] += exp2r(zA[j]) * ilhA[j];
          accB[f][j] += exp2r(zB[j]) * ilhB[j];
        }
      } else {
        int kl = 16 * f + r16;
        int word = kl >> 6, bit = kl & 63;
        #pragma unroll
        for (int j = 0; j < 4; j++){
          u64 mA = mbits[((size_t)b * SB + qr0 + j) * 32 + 2 * kt + word];
          u64 mB = mbits[((size_t)b * SB + qr1 + j) * 32 + 2 * kt + word];
          float sA = ((mA >> bit) & 1ull) ? zA[j] : NEGBIG2;
          float sB = ((mB >> bit) & 1ull) ? zB[j] : NEGBIG2;
          accA[f][j] += exp2r(sA) * ilhA[j];
          accB[f][j] += exp2r(sB) * ilhB[j];
        }
      }
    }
  }
  #pragma unroll
  for (int f = 0; f < 8; f++)
    #pragma unroll
    for (int j = 0; j < 4; j++){
      int kc = kbase + 16 * f + r16;
      avg[((size_t)b * SB + qr0 + j) * SB + kc] = accA[f][j] * 0.0625f;
      avg[((size_t)b * SB + qr1 + j) * SB + kc] = accB[f][j] * 0.0625f;
    }
}

// ---------------- launch ----------------
extern "C" void kernel_launch(void* const* d_in, const int* in_sizes, int n_in,
                              void* d_out, int out_size, void* d_ws, size_t ws_size,
                              hipStream_t stream)
{
  const float* x  = (const float*)d_in[0];
  const int* mask = (const int*)d_in[1];
  const float* Wq = (const float*)d_in[2];
  const float* bq = (const float*)d_in[3];
  const float* Wk = (const float*)d_in[4];
  const float* bk = (const float*)d_in[5];
  const float* Wv = (const float*)d_in[6];
  const float* bv = (const float*)d_in[7];
  const float* Wo = (const float*)d_in[8];
  const float* bo = (const float*)d_in[9];
  float* out = (float*)d_out;
  float* avg = out + (size_t)BB * SB * DD;

  char* ws = (char*)d_ws;
  ushort* xb   = (ushort*)(ws);                 // [4096][1024] bf16, 8 MB
  ushort* wqb  = (ushort*)(ws + (8ull  << 20));
  ushort* wkb  = (ushort*)(ws + (10ull << 20));
  ushort* wvb  = (ushort*)(ws + (12ull << 20));
  ushort* wob  = (ushort*)(ws + (14ull << 20));
  ushort* Qb   = (ushort*)(ws + (16ull << 20)); // [B,H,S,hd] (pre-scaled by C2LOG)
  ushort* Kb   = (ushort*)(ws + (24ull << 20)); // [B,H,S,hd]
  ushort* Vtb  = (ushort*)(ws + (32ull << 20)); // [B,H,hd,S]
  ushort* att  = (ushort*)(ws + (40ull << 20)); // [B,S,D]
  float*  ilarr= (float*) (ws + (48ull << 20));
  u64*    mbits= (u64*)   (ws + (49ull << 20));

  k_prep<<<40960, 256, 0, stream>>>(x, mask, Wq, Wk, Wv, Wo,
                                    xb, mbits, wqb, wkb, wvb, wob);
  k_gemm_qkv<<<dim3(8, 32, 3), 256, 0, stream>>>(xb, wqb, wkb, wvb,
                                                 bq, bk, bv, Qb, Kb, Vtb);
  k_flash<<<256, 512, 0, stream>>>(Qb, Kb, Vtb, mbits, att, ilarr);
  k_avg_out<<<384, 512, 0, stream>>>(att, wob, bo, out, Qb, Kb, mbits, ilarr, avg);
}

// Round 18
// 157.253 us; speedup vs baseline: 1.1584x; 1.1584x over previous
//
#include <hip/hip_runtime.h>
#include <cstdint>

typedef __bf16 bf16x8 __attribute__((ext_vector_type(8)));
typedef __bf16 bf16x4 __attribute__((ext_vector_type(4)));
typedef short  s16x8  __attribute__((ext_vector_type(8)));
typedef float  f32x4  __attribute__((ext_vector_type(4)));
typedef unsigned int uint32;
typedef uint32 u32x2 __attribute__((ext_vector_type(2)));
typedef unsigned long long u64;

#define SB 2048
#define DD 1024
#define HH 16
#define HDD 64
#define BB 2
#define C2LOG 0.2434547882f        /* (1.35/sqrt(64)) * log2(e)  — folded into Q */
#define NEGBIG2 (-1.9476383e9f)    /* -1e9 * 1.35 * log2(e) */

__device__ __forceinline__ ushort f2bf(float f){
  uint32 u = __builtin_bit_cast(uint32, f);
  u += 0x7fffu + ((u >> 16) & 1u);
  return (ushort)(u >> 16);
}
__device__ __forceinline__ bf16x8 ldb128(const void* p){
  return __builtin_bit_cast(bf16x8, *(const s16x8*)p);
}
__device__ __forceinline__ void gl_lds16(const void* g, void* l){
  __builtin_amdgcn_global_load_lds((const __attribute__((address_space(1))) void*)g,
                                   (__attribute__((address_space(3))) void*)l, 16, 0, 0);
}
// raw v_exp_f32 (D = 2^S0)
__device__ __forceinline__ float exp2r(float x){
  float r; asm("v_exp_f32 %0, %1" : "=v"(r) : "v"(x)); return r;
}

// ---------------- fused prep: pack mask + cvt x + cvt 4 weights --------------
__global__ __launch_bounds__(256) void k_prep(
    const float* __restrict__ x, const int* __restrict__ mask,
    const float* __restrict__ Wq, const float* __restrict__ Wk,
    const float* __restrict__ Wv, const float* __restrict__ Wo,
    ushort* __restrict__ xb, u64* __restrict__ bits,
    ushort* __restrict__ wqb, ushort* __restrict__ wkb,
    ushort* __restrict__ wvb, ushort* __restrict__ wob)
{
  int bid = blockIdx.x;
  if (bid < 32768){
    int i = bid * 256 + threadIdx.x;
    u64 bm = __ballot(mask[i] != 0);
    if ((threadIdx.x & 63) == 0) bits[i >> 6] = bm;
  } else if (bid < 36864){
    int i = (bid - 32768) * 256 + threadIdx.x;
    float4 v = ((const float4*)x)[i];
    ushort4 o;
    o.x = f2bf(v.x); o.y = f2bf(v.y); o.z = f2bf(v.z); o.w = f2bf(v.w);
    ((ushort4*)xb)[i] = o;
  } else {
    int sub = bid - 36864;
    int zz = sub >> 10;
    const float* in = (zz == 0) ? Wq : (zz == 1) ? Wk : (zz == 2) ? Wv : Wo;
    ushort* out     = (zz == 0) ? wqb : (zz == 1) ? wkb : (zz == 2) ? wvb : wob;
    int i = (sub & 1023) * 256 + threadIdx.x;
    float4 v = ((const float4*)in)[i];
    ushort4 o;
    o.x = f2bf(v.x); o.y = f2bf(v.y); o.z = f2bf(v.z); o.w = f2bf(v.w);
    ((ushort4*)out)[i] = o;
  }
}

// ---------------- generic GEMM (double-buffered): C = (A W^T + bias)*scl -----
template<int MODE>
__device__ __forceinline__ void gemm_body(
    const ushort* __restrict__ A, const ushort* __restrict__ W,
    const float* __restrict__ bias, float scl,
    ushort* __restrict__ outp, float* __restrict__ outf,
    int rowBase, int colBase, ushort* lsA, ushort* lsB)
{
  const int t = threadIdx.x;
  const int l = t & 63, w = t >> 6;
  const int g16 = l >> 4, r16 = l & 15;
  const int wr = w >> 1, wc = w & 1;
  f32x4 zero = {0.f, 0.f, 0.f, 0.f};
  f32x4 acc[4][4];
  #pragma unroll
  for (int m = 0; m < 4; m++)
    #pragma unroll
    for (int n = 0; n < 4; n++) acc[m][n] = zero;

  auto stage = [&](int kt, int buf){
    #pragma unroll
    for (int i = 0; i < 2; i++){
      int c = t + i * 256;
      int row = c >> 2, cin = c & 3;
      int g = cin ^ ((row >> 1) & 3);
      gl_lds16(A + (size_t)(rowBase + row) * DD + kt * 32 + g * 8, (char*)lsA + buf * 8192 + c * 16);
      gl_lds16(W + (size_t)(colBase + row) * DD + kt * 32 + g * 8, (char*)lsB + buf * 8192 + c * 16);
    }
  };
  stage(0, 0);
  int cur = 0;
  for (int kt = 0; kt < 32; ++kt){
    __syncthreads();
    if (kt + 1 < 32) stage(kt + 1, cur ^ 1);
    bf16x8 af[4], bfr[4];
    #pragma unroll
    for (int m = 0; m < 4; m++){
      int row = wr * 64 + m * 16 + r16;
      af[m] = ldb128((char*)lsA + cur * 8192 + row * 64 + ((g16 ^ ((row >> 1) & 3)) << 4));
    }
    #pragma unroll
    for (int n = 0; n < 4; n++){
      int row = wc * 64 + n * 16 + r16;
      bfr[n] = ldb128((char*)lsB + cur * 8192 + row * 64 + ((g16 ^ ((row >> 1) & 3)) << 4));
    }
    #pragma unroll
    for (int m = 0; m < 4; m++)
      #pragma unroll
      for (int n = 0; n < 4; n++)
        acc[m][n] = __builtin_amdgcn_mfma_f32_16x16x32_bf16(af[m], bfr[n], acc[m][n], 0, 0, 0);
    cur ^= 1;
  }
  #pragma unroll
  for (int m = 0; m < 4; m++){
    #pragma unroll
    for (int n = 0; n < 4; n++){
      int ng = colBase + wc * 64 + n * 16 + r16;
      float bval = bias[ng];
      if (MODE == 2){
        int h = ng >> 6, d = ng & 63;
        int s0 = rowBase + wr * 64 + m * 16 + g16 * 4;
        int b = s0 >> 11, s = s0 & 2047;
        ushort4 o;
        o.x = f2bf((acc[m][n][0] + bval) * scl);
        o.y = f2bf((acc[m][n][1] + bval) * scl);
        o.z = f2bf((acc[m][n][2] + bval) * scl);
        o.w = f2bf((acc[m][n][3] + bval) * scl);
        *(ushort4*)(outp + ((size_t)(b * HH + h) * HDD + d) * SB + s) = o;
      } else {
        #pragma unroll
        for (int j = 0; j < 4; j++){
          int r = rowBase + wr * 64 + m * 16 + g16 * 4 + j;
          float v = (acc[m][n][j] + bval) * scl;
          if (MODE == 0){
            int h = ng >> 6, d = ng & 63;
            int b = r >> 11, s = r & 2047;
            outp[(((size_t)(b * HH + h) * SB + s) << 6) + d] = f2bf(v);
          } else {
            outf[(size_t)r * DD + ng] = v;
          }
        }
      }
    }
  }
}

// XCD-aware 8x4 patch decode (bijective)
__device__ __forceinline__ void xcd_patch2(int bid, int& rowBase, int& colBase){
  int xcd = bid & 7, i = bid >> 3;
  rowBase = ((xcd & 3) * 8 + (i & 7)) * 128;
  colBase = ((xcd >> 2) * 4 + (i >> 3)) * 128;
}

// fused QKV projection: z=0 -> Q (scaled), z=1 -> K, z=2 -> Vt (transposed)
__global__ __launch_bounds__(256) void k_gemm_qkv(
    const ushort* __restrict__ A,
    const ushort* __restrict__ Wq, const ushort* __restrict__ Wk, const ushort* __restrict__ Wv,
    const float* __restrict__ bq, const float* __restrict__ bk, const float* __restrict__ bv,
    ushort* __restrict__ Q, ushort* __restrict__ K, ushort* __restrict__ Vt)
{
  __shared__ ushort lsA[2][4096];
  __shared__ ushort lsB[2][4096];
  int rowBase, colBase;
  xcd_patch2(blockIdx.x + blockIdx.y * 8, rowBase, colBase);
  int z = blockIdx.z;
  if (z == 0)      gemm_body<0>(A, Wq, bq, C2LOG, Q, nullptr, rowBase, colBase, &lsA[0][0], &lsB[0][0]);
  else if (z == 1) gemm_body<0>(A, Wk, bk, 1.0f, K, nullptr, rowBase, colBase, &lsA[0][0], &lsB[0][0]);
  else             gemm_body<2>(A, Wv, bv, 1.0f, Vt, nullptr, rowBase, colBase, &lsA[0][0], &lsB[0][0]);
}

// ---------------- flash attention: 8 waves x 32 q, KVBLK=128 super-tiles -----
// (EXACT r16-passing body)
__device__ __forceinline__ void stage_kv2(const ushort* __restrict__ Kp,
                                          const ushort* __restrict__ Vp,
                                          ushort* dK, ushort* dV, int t){
  #pragma unroll
  for (int i = 0; i < 2; ++i){
    int c = t + 512 * i;
    int r = c >> 3, g = (c & 7) ^ (r & 7);
    gl_lds16(Kp + (size_t)r * HDD + g * 8, (char*)dK + c * 16);
  }
  #pragma unroll
  for (int i = 0; i < 2; ++i){
    int c = t + 512 * i;
    int r = c >> 4, cc = c & 15;
    int g = ((cc & 7) ^ (r & 7)) | (cc & 8);
    gl_lds16(Vp + (size_t)r * SB + g * 8, (char*)dV + c * 16);
  }
}

__global__ __launch_bounds__(512) void k_flash(
    const ushort* __restrict__ Q, const ushort* __restrict__ K, const ushort* __restrict__ Vt,
    const u64* __restrict__ mbits,
    ushort* __restrict__ att, float* __restrict__ ilarr)
{
  __shared__ ushort lsK[2][8192];
  __shared__ ushort lsV[2][10240];   // 80 rows x 128 cols
  __shared__ ushort lsP[8][2048];
  const int t = threadIdx.x;
  const int l = t & 63, w = t >> 6;
  const int g16 = l >> 4, r16 = l & 15;
  const int bid = blockIdx.x;
  const int qt = (bid >> 3) & 7;
  const int hb = (bid >> 6) * 8 + (bid & 7);
  const int h = hb & 15, b = hb >> 4;
  const size_t ho = ((size_t)(b * HH + h)) * SB * HDD;
  const int qa = qt * 256 + w * 32 + r16;   // q-group a
  const int qb = qa + 16;                   // q-group b

  bf16x8 aqa[2], aqb[2];
  #pragma unroll
  for (int ks = 0; ks < 2; ++ks){
    aqa[ks] = ldb128(Q + ho + (size_t)qa * HDD + ks * 32 + g16 * 8);
    aqb[ks] = ldb128(Q + ho + (size_t)qb * HDD + ks * 32 + g16 * 8);
  }
  const u64* mpa = mbits + ((size_t)b * SB + qa) * 32;
  const u64* mpb = mbits + ((size_t)b * SB + qb) * 32;

  f32x4 zero = {0.f, 0.f, 0.f, 0.f};
  f32x4 accA[4], accB[4], accLA = zero, accLB = zero;
  #pragma unroll
  for (int c = 0; c < 4; c++){ accA[c] = zero; accB[c] = zero; }

  if (t < 256) lsV[t >> 7][8192 + (t & 127)] = 0x3F80;

  const ushort* Kb = K + ho;
  const ushort* Vb = Vt + ho;
  stage_kv2(Kb, Vb, &lsK[0][0], &lsV[0][0], t);

  int cur = 0;
  for (int kk = 0; kk < 16; ++kk){
    __syncthreads();
    if (kk + 1 < 16)
      stage_kv2(Kb + (size_t)(kk + 1) * 128 * HDD, Vb + (size_t)(kk + 1) * 128,
                &lsK[cur ^ 1][0], &lsV[cur ^ 1][0], t);

    #pragma unroll
    for (int h2 = 0; h2 < 2; ++h2){
      const char* lk = (const char*)&lsK[cur][0] + h2 * 8192;
      const char* lv = (const char*)&lsV[cur][0] + h2 * 128;
      char* lp = (char*)&lsP[w][0];

      f32x4 za[4], zb[4];
      __builtin_amdgcn_s_setprio(1);
      #pragma unroll
      for (int f = 0; f < 4; ++f){
        za[f] = zero; zb[f] = zero;
        int row = 16 * f + r16;
        #pragma unroll
        for (int ks = 0; ks < 2; ++ks){
          bf16x8 kf = ldb128(lk + row * 128 + ((((ks << 2) + g16) ^ (row & 7)) << 4));
          za[f] = __builtin_amdgcn_mfma_f32_16x16x32_bf16(kf, aqa[ks], za[f], 0, 0, 0);
          zb[f] = __builtin_amdgcn_mfma_f32_16x16x32_bf16(kf, aqb[ks], zb[f], 0, 0, 0);
        }
      }
      __builtin_amdgcn_s_setprio(0);

      u64 mwa = mpa[2 * kk + h2], mwb = mpb[2 * kk + h2];
      float pa[4][4], pb[4][4];
      if (__all((mwa & mwb) == ~0ull)){
        #pragma unroll
        for (int f = 0; f < 4; ++f)
          #pragma unroll
          for (int j = 0; j < 4; ++j){
            pa[f][j] = exp2r(za[f][j]);
            pb[f][j] = exp2r(zb[f][j]);
          }
      } else {
        #pragma unroll
        for (int f = 0; f < 4; ++f)
          #pragma unroll
          for (int j = 0; j < 4; ++j){
            int bit = 16 * f + 4 * g16 + j;
            pa[f][j] = exp2r(((mwa >> bit) & 1ull) ? za[f][j] : NEGBIG2);
            pb[f][j] = exp2r(((mwb >> bit) & 1ull) ? zb[f][j] : NEGBIG2);
          }
      }

      {
        int wba = r16 * 128 + ((g16 & 1) << 3);
        int wbb = (r16 + 16) * 128 + ((g16 & 1) << 3);
        #pragma unroll
        for (int f = 0; f < 4; ++f){
          bf16x4 va_ = { (__bf16)pa[f][0], (__bf16)pa[f][1], (__bf16)pa[f][2], (__bf16)pa[f][3] };
          bf16x4 vb_ = { (__bf16)pb[f][0], (__bf16)pb[f][1], (__bf16)pb[f][2], (__bf16)pb[f][3] };
          int sw = ((2 * f + (g16 >> 1)) ^ (r16 & 7)) << 4;
          *(u32x2*)(lp + wba + sw) = __builtin_bit_cast(u32x2, va_);
          *(u32x2*)(lp + wbb + sw) = __builtin_bit_cast(u32x2, vb_);
        }
      }
      bf16x8 pfA[2], pfB[2];
      #pragma unroll
      for (int ks = 0; ks < 2; ++ks){
        int sw = (((ks << 2) + g16) ^ (r16 & 7)) << 4;
        pfA[ks] = ldb128(lp + r16 * 128 + sw);
        pfB[ks] = ldb128(lp + (r16 + 16) * 128 + sw);
      }

      __builtin_amdgcn_s_setprio(1);
      #pragma unroll
      for (int c = 0; c < 4; ++c){
        int row = 16 * c + r16;
        #pragma unroll
        for (int ks = 0; ks < 2; ++ks){
          bf16x8 vf = ldb128(lv + row * 256 + ((((ks << 2) + g16) ^ (row & 7)) << 4));
          accA[c] = __builtin_amdgcn_mfma_f32_16x16x32_bf16(vf, pfA[ks], accA[c], 0, 0, 0);
          accB[c] = __builtin_amdgcn_mfma_f32_16x16x32_bf16(vf, pfB[ks], accB[c], 0, 0, 0);
        }
      }
      {
        int row = 64 + r16;
        #pragma unroll
        for (int ks = 0; ks < 2; ++ks){
          bf16x8 of = ldb128(lv + row * 256 + ((((ks << 2) + g16) ^ (row & 7)) << 4));
          accLA = __builtin_amdgcn_mfma_f32_16x16x32_bf16(of, pfA[ks], accLA, 0, 0, 0);
          accLB = __builtin_amdgcn_mfma_f32_16x16x32_bf16(of, pfB[ks], accLB, 0, 0, 0);
        }
      }
      __builtin_amdgcn_s_setprio(0);
    }
    cur ^= 1;
  }

  float ila = 1.0f / __shfl(accLA[0], r16);
  float ilb = 1.0f / __shfl(accLB[0], r16);
  #pragma unroll
  for (int c = 0; c < 4; ++c){
    ushort4 oa, ob;
    oa.x = f2bf(accA[c][0] * ila); oa.y = f2bf(accA[c][1] * ila);
    oa.z = f2bf(accA[c][2] * ila); oa.w = f2bf(accA[c][3] * ila);
    ob.x = f2bf(accB[c][0] * ilb); ob.y = f2bf(accB[c][1] * ilb);
    ob.z = f2bf(accB[c][2] * ilb); ob.w = f2bf(accB[c][3] * ilb);
    *(ushort4*)(att + ((size_t)b * SB + qa) * DD + h * HDD + c * 16 + 4 * g16) = oa;
    *(ushort4*)(att + ((size_t)b * SB + qb) * DD + h * HDD + c * 16 + 4 * g16) = ob;
  }
  if (g16 == 0){
    ilarr[(size_t)(b * HH + h) * SB + qa] = ila;
    ilarr[(size_t)(b * HH + h) * SB + qb] = ilb;
  }
}

// ---------------- fused avg + out-GEMM (grid-range split, LPT order) ---------
// blocks [0,512): avg body (long blocks first for tail packing).
// blocks [512,768): out-GEMM (waves 0-3 compute; waves 4-7 run 32 barriers).
__global__ __launch_bounds__(512) void k_avg_out(
    const ushort* __restrict__ att, const ushort* __restrict__ wob,
    const float* __restrict__ bo, float* __restrict__ out,
    const ushort* __restrict__ Q, const ushort* __restrict__ K,
    const u64* __restrict__ mbits,
    const float* __restrict__ ilarr, float* __restrict__ avg)
{
  __shared__ ushort smem[32768];   // 64 KB: avg uses all; gemm uses first 32 KB
  const int bid = blockIdx.x;
  const int t = threadIdx.x;

  if (bid >= 512){
    // ---- out-GEMM block ----
    int rowBase, colBase;
    xcd_patch2(bid - 512, rowBase, colBase);
    if (t < 256){
      gemm_body<1>(att, wob, bo, 1.0f, nullptr, out, rowBase, colBase,
                   smem, smem + 8192);
    } else {
      #pragma unroll 1
      for (int k = 0; k < 32; ++k) __syncthreads();
    }
    return;
  }

  // ---- avg block ----
  const int bid2 = bid;
  const int kt = bid2 & 15, qt = (bid2 >> 4) & 15, b = bid2 >> 8;
  ushort* lsQ0 = smem;            // [2][8192]
  ushort* lsK0 = smem + 16384;    // [2][8192]
  const int l = t & 63, w = t >> 6;
  const int g16 = l >> 4, r16 = l & 15;
  const int qbase = qt * 128, kbase = kt * 128;
  const int qr0 = qbase + w * 16 + g16 * 4;

  u64 mw[4][2];
  #pragma unroll
  for (int j = 0; j < 4; j++){
    mw[j][0] = mbits[((size_t)b * SB + qr0 + j) * 32 + 2 * kt];
    mw[j][1] = mbits[((size_t)b * SB + qr0 + j) * 32 + 2 * kt + 1];
  }
  bool fast = __all((mw[0][0] & mw[0][1] & mw[1][0] & mw[1][1] &
                     mw[2][0] & mw[2][1] & mw[3][0] & mw[3][1]) == ~0ull);

  f32x4 zero = {0.f, 0.f, 0.f, 0.f};
  f32x4 acc[8];
  #pragma unroll
  for (int f = 0; f < 8; f++) acc[f] = zero;

  const size_t hstep = (size_t)SB * HDD;
  const ushort* Qp = Q + (size_t)b * HH * hstep + (size_t)qbase * HDD;
  const ushort* Kp = K + (size_t)b * HH * hstep + (size_t)kbase * HDD;

  for (int hh = 0; hh < 8; ++hh){
    __syncthreads();
    #pragma unroll
    for (int p = 0; p < 2; ++p){
      int h = 2 * hh + p;
      #pragma unroll
      for (int i = 0; i < 2; ++i){
        int c = t + i * 512;
        int r = c >> 3, g = (c & 7) ^ (r & 7);
        gl_lds16(Qp + (size_t)h * hstep + (size_t)r * HDD + g * 8, (char*)(lsQ0 + p * 8192) + c * 16);
        gl_lds16(Kp + (size_t)h * hstep + (size_t)r * HDD + g * 8, (char*)(lsK0 + p * 8192) + c * 16);
      }
    }
    __syncthreads();

    #pragma unroll
    for (int p = 0; p < 2; ++p){
      int h = 2 * hh + p;
      int qrow = w * 16 + r16;
      bf16x8 a0 = ldb128((char*)(lsQ0 + p * 8192) + qrow * 128 + (((0 + g16) ^ (qrow & 7)) << 4));
      bf16x8 a1 = ldb128((char*)(lsQ0 + p * 8192) + qrow * 128 + (((4 + g16) ^ (qrow & 7)) << 4));
      float ilh[4];
      #pragma unroll
      for (int j = 0; j < 4; j++)
        ilh[j] = ilarr[(size_t)(b * HH + h) * SB + qr0 + j];

      #pragma unroll
      for (int f = 0; f < 8; ++f){
        int row = 16 * f + r16;
        bf16x8 b0 = ldb128((char*)(lsK0 + p * 8192) + row * 128 + (((0 + g16) ^ (row & 7)) << 4));
        bf16x8 b1 = ldb128((char*)(lsK0 + p * 8192) + row * 128 + (((4 + g16) ^ (row & 7)) << 4));
        f32x4 z = zero;
        z = __builtin_amdgcn_mfma_f32_16x16x32_bf16(a0, b0, z, 0, 0, 0);
        z = __builtin_amdgcn_mfma_f32_16x16x32_bf16(a1, b1, z, 0, 0, 0);
        if (fast){
          #pragma unroll
          for (int j = 0; j < 4; j++)
            acc[f][j] += exp2r(z[j]) * ilh[j];
        } else {
          int kl = 16 * f + r16;
          int word = kl >> 6, bit = kl & 63;
          #pragma unroll
          for (int j = 0; j < 4; j++){
            float s = ((mw[j][word] >> bit) & 1ull) ? z[j] : NEGBIG2;
            acc[f][j] += exp2r(s) * ilh[j];
          }
        }
      }
    }
  }
  #pragma unroll
  for (int f = 0; f < 8; f++)
    #pragma unroll
    for (int j = 0; j < 4; j++){
      int qr = qr0 + j;
      int kc = kbase + 16 * f + r16;
      avg[((size_t)b * SB + qr) * SB + kc] = acc[f][j] * 0.0625f;
    }
}

// ---------------- launch ----------------
extern "C" void kernel_launch(void* const* d_in, const int* in_sizes, int n_in,
                              void* d_out, int out_size, void* d_ws, size_t ws_size,
                              hipStream_t stream)
{
  const float* x  = (const float*)d_in[0];
  const int* mask = (const int*)d_in[1];
  const float* Wq = (const float*)d_in[2];
  const float* bq = (const float*)d_in[3];
  const float* Wk = (const float*)d_in[4];
  const float* bk = (const float*)d_in[5];
  const float* Wv = (const float*)d_in[6];
  const float* bv = (const float*)d_in[7];
  const float* Wo = (const float*)d_in[8];
  const float* bo = (const float*)d_in[9];
  float* out = (float*)d_out;
  float* avg = out + (size_t)BB * SB * DD;

  char* ws = (char*)d_ws;
  ushort* xb   = (ushort*)(ws);                 // [4096][1024] bf16, 8 MB
  ushort* wqb  = (ushort*)(ws + (8ull  << 20));
  ushort* wkb  = (ushort*)(ws + (10ull << 20));
  ushort* wvb  = (ushort*)(ws + (12ull << 20));
  ushort* wob  = (ushort*)(ws + (14ull << 20));
  ushort* Qb   = (ushort*)(ws + (16ull << 20)); // [B,H,S,hd] (pre-scaled by C2LOG)
  ushort* Kb   = (ushort*)(ws + (24ull << 20)); // [B,H,S,hd]
  ushort* Vtb  = (ushort*)(ws + (32ull << 20)); // [B,H,hd,S]
  ushort* att  = (ushort*)(ws + (40ull << 20)); // [B,S,D]
  float*  ilarr= (float*) (ws + (48ull << 20));
  u64*    mbits= (u64*)   (ws + (49ull << 20));

  k_prep<<<40960, 256, 0, stream>>>(x, mask, Wq, Wk, Wv, Wo,
                                    xb, mbits, wqb, wkb, wvb, wob);
  k_gemm_qkv<<<dim3(8, 32, 3), 256, 0, stream>>>(xb, wqb, wkb, wvb,
                                                 bq, bk, bv, Qb, Kb, Vtb);
  k_flash<<<256, 512, 0, stream>>>(Qb, Kb, Vtb, mbits, att, ilarr);
  k_avg_out<<<768, 512, 0, stream>>>(att, wob, bo, out, Qb, Kb, mbits, ilarr, avg);
}